// Round 5
// baseline (381.332 us; speedup 1.0000x reference)
//
#include <hip/hip_runtime.h>
#include <math.h>

#define BB 16
#define CC 512
#define HWN 4096
#define INNER 256
#define EPSV 1e-5f

__device__ __forceinline__ float wave_sum(float s) {
    for (int off = 32; off; off >>= 1) s += __shfl_down(s, off);
    return s;
}
__device__ __forceinline__ float block_sum(float v, volatile float* s_red) {
    for (int off = 32; off; off >>= 1) v += __shfl_down(v, off);
    __syncthreads();
    if ((threadIdx.x & 63) == 0) s_red[threadIdx.x >> 6] = v;
    __syncthreads();
    return s_red[0] + s_red[1] + s_red[2] + s_red[3];
}
__device__ __forceinline__ float block_max(float v, volatile float* s_red) {
    for (int off = 32; off; off >>= 1) v = fmaxf(v, __shfl_down(v, off));
    __syncthreads();
    if ((threadIdx.x & 63) == 0) s_red[threadIdx.x >> 6] = v;
    __syncthreads();
    return fmaxf(fmaxf(s_red[0], s_red[1]), fmaxf(s_red[2], s_red[3]));
}
__device__ __forceinline__ float block_sum8(float v, volatile float* s_red) {
    for (int off = 32; off; off >>= 1) v += __shfl_down(v, off);
    __syncthreads();
    if ((threadIdx.x & 63) == 0) s_red[threadIdx.x >> 6] = v;
    __syncthreads();
    return ((s_red[0] + s_red[1]) + (s_red[2] + s_red[3]))
         + ((s_red[4] + s_red[5]) + (s_red[6] + s_red[7]));
}
__device__ __forceinline__ float fsigmoid(float v) {
    return __builtin_amdgcn_rcpf(1.f + __expf(-v));
}

// ---- kA: pass 1 over x. grid (16 hw-tiles of 256, 4 c-quarters, 16 b) = 1024 blocks.
// cm_part[b][q][hw]      = sum_{c in quarter} x[b,c,hw] * Wcq[c]
// xsum_part[b][hwblk][c] = sum_{hw in 256-tile} x[b,c,hw]
__global__ __launch_bounds__(256) void kA(
    const float* __restrict__ x, const float* __restrict__ wcq,
    float* __restrict__ cm_part, float* __restrict__ xsum_part)
{
    const int t = threadIdx.x, lane = t & 63, w = t >> 6;
    const int hw0 = blockIdx.x * 256;
    const int q   = blockIdx.y;
    const int c0  = q * 128;
    const int b   = blockIdx.z;
    __shared__ float s_w[128];
    __shared__ float s_cm[4][256];
    __shared__ float s_part[4][32][65];   // [wave][ci][lane], pitch 65: conflict-free
    if (t < 128) s_w[t] = wcq[c0 + t];
    __syncthreads();
    const float* xb = x + ((size_t)b * CC + c0) * HWN + hw0 + lane * 4;
    float4 acc = {0,0,0,0};
    #pragma unroll 8
    for (int ci = 0; ci < 32; ++ci) {
        const int cl = w + ci * 4;
        float4 v = *(const float4*)(xb + (size_t)cl * HWN);
        const float wc = s_w[cl];
        acc.x = fmaf(v.x, wc, acc.x); acc.y = fmaf(v.y, wc, acc.y);
        acc.z = fmaf(v.z, wc, acc.z); acc.w = fmaf(v.w, wc, acc.w);
        s_part[w][ci][lane] = (v.x + v.y) + (v.z + v.w);
    }
    // wave-local transpose reduce: lanes 0-31 sum cols 0-31 of row r, 32-63 cols 32-63
    {
        const int r  = lane & 31;
        const int j0 = (lane >> 5) * 32;
        float xs = 0.f;
        #pragma unroll
        for (int j = 0; j < 32; ++j) xs += s_part[w][r][j0 + j];
        xs += __shfl_down(xs, 32);
        if (lane < 32)
            xsum_part[((size_t)b * 16 + blockIdx.x) * CC + c0 + w + r * 4] = xs;
    }
    *(float4*)&s_cm[w][lane * 4] = acc;
    __syncthreads();
    cm_part[((size_t)b * 4 + q) * HWN + hw0 + t] =
        (s_cm[0][t] + s_cm[1][t]) + (s_cm[2][t] + s_cm[3][t]);
}

// ---- kBf: grid (16, 3).
// y<2:  reduce xsum -> avg_logits (thread-per-k) -> softmax -> wsv_eff half y
// y==2: cm softmax stats
__global__ __launch_bounds__(256) void kBf(
    const float* __restrict__ Wsq, const float* __restrict__ Wsv,
    const float* __restrict__ cm_part, const float* __restrict__ xsum_part,
    float* __restrict__ cmstats, float* __restrict__ wsv_eff)
{
    const int b = blockIdx.x, t = threadIdx.x;
    __shared__ float s_red[4];
    if (blockIdx.y == 2) {
        const float* p0 = cm_part + (size_t)b * 4 * HWN;
        const float* p1 = p0 + HWN;
        const float* p2 = p1 + HWN;
        const float* p3 = p2 + HWN;
        float lmax = -1e30f;
        #pragma unroll 4
        for (int i = t; i < HWN; i += 256)
            lmax = fmaxf(lmax, (p0[i] + p1[i]) + (p2[i] + p3[i]));
        lmax = block_max(lmax, s_red);
        float lsum = 0.f;
        #pragma unroll 4
        for (int i = t; i < HWN; i += 256)
            lsum += __expf((p0[i] + p1[i]) + (p2[i] + p3[i]) - lmax);
        lsum = block_sum(lsum, s_red);
        if (t == 0) {
            cmstats[2 * b]     = lmax;
            cmstats[2 * b + 1] = __builtin_amdgcn_rcpf(lsum);
        }
        return;
    }
    __shared__ float s_v[CC];
    __shared__ float s_sm[INNER];
    // 1. reduce xsum partials (16 hw-blocks)
    {
        const float* xp = xsum_part + (size_t)b * 16 * CC;
        float a0 = 0.f, a1 = 0.f;
        #pragma unroll
        for (int blk = 0; blk < 16; ++blk) {
            a0 += xp[blk * CC + t];
            a1 += xp[blk * CC + t + 256];
        }
        s_v[t] = a0; s_v[t + 256] = a1;
    }
    __syncthreads();
    // 2. avg_logits[k=t] = Wsq[t,:512] . s_v / HWN  (thread-per-k, LDS broadcast)
    float a;
    {
        const float* wr = Wsq + (size_t)t * CC;
        float d = 0.f;
        #pragma unroll 8
        for (int k = 0; k < CC; ++k) d = fmaf(wr[k], s_v[k], d);
        a = d * (1.0f / HWN);
    }
    // 3. softmax over 256 inner channels
    float m = block_max(a, s_red);
    float e = __expf(a - m);
    float s2 = block_sum(e, s_red);
    s_sm[t] = e * __builtin_amdgcn_rcpf(s2);
    __syncthreads();
    // 4. wsv_eff half
    {
        const int c = blockIdx.y * 256 + t;
        float acc = 0.f;
        #pragma unroll 8
        for (int k = 0; k < INNER; ++k)
            acc = fmaf(s_sm[k], Wsv[(size_t)k * CC + c], acc);
        wsv_eff[b * CC + c] = acc;
    }
}

// ---- kC: pass 2 over x. grid (16, 4, 16) = 1024 blocks.
// ctx_part[b][q][hw]   = sum_{c quarter} x * wsv_eff[c]
// xw_part[b][hwblk][c] = sum_{hw 256-tile} x * softmax(cm)[hw]
__global__ __launch_bounds__(256) void kC(
    const float* __restrict__ x, const float* __restrict__ wsv_eff,
    const float* __restrict__ cm_part, const float* __restrict__ cmstats,
    float* __restrict__ ctx_part, float* __restrict__ xw_part)
{
    const int t = threadIdx.x, lane = t & 63, w = t >> 6;
    const int hw0 = blockIdx.x * 256;
    const int q   = blockIdx.y;
    const int c0  = q * 128;
    const int b   = blockIdx.z;
    __shared__ float s_w[128];
    __shared__ float s_m[256];
    __shared__ float s_cm[4][256];
    __shared__ float s_part[4][32][65];
    if (t < 128) s_w[t] = wsv_eff[b * CC + c0 + t];
    {
        const float cmax = cmstats[2 * b], crinv = cmstats[2 * b + 1];
        const size_t cb = (size_t)b * 4 * HWN + hw0 + t;
        const float cmv = (cm_part[cb] + cm_part[cb + HWN])
                        + (cm_part[cb + 2 * HWN] + cm_part[cb + 3 * HWN]);
        s_m[t] = __expf(cmv - cmax) * crinv;
    }
    __syncthreads();
    float4 mreg = *(const float4*)&s_m[lane * 4];
    const float* xb = x + ((size_t)b * CC + c0) * HWN + hw0 + lane * 4;
    float4 acc = {0,0,0,0};
    #pragma unroll 8
    for (int ci = 0; ci < 32; ++ci) {
        const int cl = w + ci * 4;
        float4 v = *(const float4*)(xb + (size_t)cl * HWN);
        const float wc = s_w[cl];
        acc.x = fmaf(v.x, wc, acc.x); acc.y = fmaf(v.y, wc, acc.y);
        acc.z = fmaf(v.z, wc, acc.z); acc.w = fmaf(v.w, wc, acc.w);
        s_part[w][ci][lane] =
            fmaf(v.x,mreg.x, fmaf(v.y,mreg.y, fmaf(v.z,mreg.z, v.w*mreg.w)));
    }
    {
        const int r  = lane & 31;
        const int j0 = (lane >> 5) * 32;
        float xs = 0.f;
        #pragma unroll
        for (int j = 0; j < 32; ++j) xs += s_part[w][r][j0 + j];
        xs += __shfl_down(xs, 32);
        if (lane < 32)
            xw_part[((size_t)b * 16 + blockIdx.x) * CC + c0 + w + r * 4] = xs;
    }
    *(float4*)&s_cm[w][lane * 4] = acc;
    __syncthreads();
    ctx_part[((size_t)b * 4 + q) * HWN + hw0 + t] =
        (s_cm[0][t] + s_cm[1][t]) + (s_cm[2][t] + s_cm[3][t]);
}

// ---- kDf: grid (16, 5), 512 threads.
// y<4:  ctxsig[b,hw] = sigmoid(sum_q ctx_part[b,q,hw]) for hw quarter y
// y==4: reduce xw -> context (thread-per-k) -> z (thread-per-o) -> LN -> mask
__global__ __launch_bounds__(512) void kDf(
    const float* __restrict__ Wcv, const float* __restrict__ Wcz,
    const float* __restrict__ gamma, const float* __restrict__ beta,
    const float* __restrict__ ctx_part, const float* __restrict__ xw_part,
    float* __restrict__ ctxsig, float* __restrict__ maskbuf)
{
    const int b = blockIdx.x, t = threadIdx.x;
    if (blockIdx.y < 4) {
        const int hw = blockIdx.y * 1024 + t * 2;
        const size_t pb = (size_t)b * 4 * HWN + hw;
        float2 p0 = *(const float2*)(ctx_part + pb);
        float2 p1 = *(const float2*)(ctx_part + pb + HWN);
        float2 p2 = *(const float2*)(ctx_part + pb + 2 * HWN);
        float2 p3 = *(const float2*)(ctx_part + pb + 3 * HWN);
        float2 sg;
        sg.x = fsigmoid((p0.x + p1.x) + (p2.x + p3.x));
        sg.y = fsigmoid((p0.y + p1.y) + (p2.y + p3.y));
        *(float2*)(ctxsig + (size_t)b * HWN + hw) = sg;
        return;
    }
    __shared__ float s_red[8];
    __shared__ float s_v[CC];
    __shared__ float s_ctx[INNER];
    // 1. reduce xw partials (all 512 threads)
    {
        const float* xp = xw_part + (size_t)b * 16 * CC;
        float a0 = 0.f;
        #pragma unroll
        for (int blk = 0; blk < 16; ++blk) a0 += xp[blk * CC + t];
        s_v[t] = a0;
    }
    __syncthreads();
    // 2. context[k=t] = Wcv[t,:512] . s_v  (threads 0-255)
    if (t < INNER) {
        const float* wr = Wcv + (size_t)t * CC;
        float d = 0.f;
        #pragma unroll 8
        for (int k = 0; k < CC; ++k) d = fmaf(wr[k], s_v[k], d);
        s_ctx[t] = d;
    }
    __syncthreads();
    // 3. z[o=t] = Wcz[t,:256] . context  (all 512 threads)
    float z;
    {
        const float* wr = Wcz + (size_t)t * INNER;
        float d = 0.f;
        #pragma unroll 8
        for (int k = 0; k < INNER; ++k) d = fmaf(wr[k], s_ctx[k], d);
        z = d;
    }
    // 4. LayerNorm over 512 -> sigmoid mask
    float mu = block_sum8(z, s_red) * (1.f / CC);
    float d = z - mu;
    float var = block_sum8(d * d, s_red) * (1.f / CC);
    float rstd = rsqrtf(var + EPSV);
    maskbuf[b * CC + t] = fsigmoid(fmaf(d * rstd, gamma[t], beta[t]));
}

// ---- kE: pass 3 over x. out = x * (mask[c] + ctxsig[hw]).
__global__ __launch_bounds__(256) void kE(
    const float* __restrict__ x, const float* __restrict__ ctxsig,
    const float* __restrict__ maskbuf, float* __restrict__ out)
{
    const int t  = threadIdx.x;
    const int hw = blockIdx.x * 1024 + t * 4;
    const int c0 = blockIdx.y * 16;
    const int b  = blockIdx.z;
    float4 sg = *(const float4*)(ctxsig + (size_t)b * HWN + hw);
    const float* mb = maskbuf + b * CC + c0;
    const size_t base = ((size_t)b * CC + c0) * HWN + hw;
    #pragma unroll 4
    for (int ci = 0; ci < 16; ++ci) {
        const float m = mb[ci];
        float4 xv = *(const float4*)(x + base + (size_t)ci * HWN);
        float4 o;
        o.x = xv.x * (m + sg.x);
        o.y = xv.y * (m + sg.y);
        o.z = xv.z * (m + sg.z);
        o.w = xv.w * (m + sg.w);
        *(float4*)(out + base + (size_t)ci * HWN) = o;
    }
}

extern "C" void kernel_launch(void* const* d_in, const int* in_sizes, int n_in,
                              void* d_out, int out_size, void* d_ws, size_t ws_size,
                              hipStream_t stream) {
    const float* x     = (const float*)d_in[0];
    const float* Wsq   = (const float*)d_in[1];
    const float* Wsv   = (const float*)d_in[2];
    const float* Wcq   = (const float*)d_in[3];
    const float* Wcv   = (const float*)d_in[4];
    const float* Wcz   = (const float*)d_in[5];
    const float* gamma = (const float*)d_in[6];
    const float* beta  = (const float*)d_in[7];
    float* out = (float*)d_out;
    float* ws  = (float*)d_ws;

    float* cm_part   = ws;            // [16][4][4096]  = 262144
    float* xsum_part = ws + 262144;   // [16][16][512]  = 131072 (reused as xw_part)
    float* ctx_part  = ws + 393216;   // [16][4][4096]  = 262144
    float* cmstats   = ws + 655360;   // 32
    float* wsv_eff   = ws + 655392;   // 8192
    float* ctxsig    = ws + 663584;   // [16][4096]     = 65536
    float* maskbuf   = ws + 729120;   // 8192
    // total ~737344 floats (~2.9 MiB); fully written before read — no memset

    kA<<<dim3(16, 4, BB), 256, 0, stream>>>(x, Wcq, cm_part, xsum_part);
    kBf<<<dim3(BB, 3), 256, 0, stream>>>(Wsq, Wsv, cm_part, xsum_part, cmstats, wsv_eff);
    kC<<<dim3(16, 4, BB), 256, 0, stream>>>(x, wsv_eff, cm_part, cmstats, ctx_part, xsum_part);
    kDf<<<dim3(BB, 5), 512, 0, stream>>>(Wcv, Wcz, gamma, beta, ctx_part, xsum_part, ctxsig, maskbuf);
    kE<<<dim3(4, 32, BB), 256, 0, stream>>>(x, ctxsig, maskbuf, out);
}

// Round 7
// 355.935 us; speedup vs baseline: 1.0714x; 1.0714x over previous
//
#include <hip/hip_runtime.h>
#include <math.h>

#define BB 16
#define CC 512
#define HWN 4096
#define INNER 256
#define EPSV 1e-5f

__device__ __forceinline__ float wave_sum(float s) {
    for (int off = 32; off; off >>= 1) s += __shfl_down(s, off);
    return s;
}
__device__ __forceinline__ float block_sum(float v, volatile float* s_red) {
    for (int off = 32; off; off >>= 1) v += __shfl_down(v, off);
    __syncthreads();
    if ((threadIdx.x & 63) == 0) s_red[threadIdx.x >> 6] = v;
    __syncthreads();
    return s_red[0] + s_red[1] + s_red[2] + s_red[3];
}
__device__ __forceinline__ float block_max(float v, volatile float* s_red) {
    for (int off = 32; off; off >>= 1) v = fmaxf(v, __shfl_down(v, off));
    __syncthreads();
    if ((threadIdx.x & 63) == 0) s_red[threadIdx.x >> 6] = v;
    __syncthreads();
    return fmaxf(fmaxf(s_red[0], s_red[1]), fmaxf(s_red[2], s_red[3]));
}
__device__ __forceinline__ float block_sum8(float v, volatile float* s_red) {
    for (int off = 32; off; off >>= 1) v += __shfl_down(v, off);
    __syncthreads();
    if ((threadIdx.x & 63) == 0) s_red[threadIdx.x >> 6] = v;
    __syncthreads();
    return ((s_red[0] + s_red[1]) + (s_red[2] + s_red[3]))
         + ((s_red[4] + s_red[5]) + (s_red[6] + s_red[7]));
}
__device__ __forceinline__ float fsigmoid(float v) {
    return __builtin_amdgcn_rcpf(1.f + __expf(-v));
}

// ---- kA: pass 1 over x. grid (8 hw-tiles of 512, 4 c-quarters, 16 b) = 512 blocks.
// 2KB contiguous read per (wave,row).  LDS total ~42 KB (< 64 KB).
// cm_part[b][q][hw]; xsum_part[b][hwblk][c].
__global__ __launch_bounds__(256) void kA(
    const float* __restrict__ x, const float* __restrict__ wcq,
    float* __restrict__ cm_part, float* __restrict__ xsum_part)
{
    const int t = threadIdx.x, lane = t & 63, w = t >> 6;
    const int hw0 = blockIdx.x * 512;
    const int q   = blockIdx.y;
    const int c0  = q * 128;
    const int b   = blockIdx.z;
    __shared__ float s_w[128];
    __shared__ float s_cm[4][512];
    __shared__ float s_part[4][32][65];   // [wave][ci][lane], pitch 65: conflict-free
    if (t < 128) s_w[t] = wcq[c0 + t];
    __syncthreads();
    const float* xb = x + ((size_t)b * CC + c0) * HWN + hw0 + lane * 8;
    float4 a0 = {0,0,0,0}, a1 = a0;
    #pragma unroll 4
    for (int ci = 0; ci < 32; ++ci) {
        const int cl = w + ci * 4;
        const float* p = xb + (size_t)cl * HWN;
        float4 v0 = *(const float4*)(p);
        float4 v1 = *(const float4*)(p + 4);
        const float wc = s_w[cl];
        a0.x = fmaf(v0.x, wc, a0.x); a0.y = fmaf(v0.y, wc, a0.y);
        a0.z = fmaf(v0.z, wc, a0.z); a0.w = fmaf(v0.w, wc, a0.w);
        a1.x = fmaf(v1.x, wc, a1.x); a1.y = fmaf(v1.y, wc, a1.y);
        a1.z = fmaf(v1.z, wc, a1.z); a1.w = fmaf(v1.w, wc, a1.w);
        s_part[w][ci][lane] = ((v0.x + v0.y) + (v0.z + v0.w))
                            + ((v1.x + v1.y) + (v1.z + v1.w));
    }
    // wave-local reduce: lanes 0-31 sum cols 0-31 of row r, lanes 32-63 cols 32-63
    {
        const int r = lane & 31;
        const int j0 = (lane >> 5) * 32;
        float xs = 0.f;
        #pragma unroll
        for (int j = 0; j < 32; ++j) xs += s_part[w][r][j0 + j];
        xs += __shfl_down(xs, 32);
        if (lane < 32)
            xsum_part[((size_t)b * 8 + blockIdx.x) * CC + c0 + w + r * 4] = xs;
    }
    *(float4*)&s_cm[w][lane * 8]     = a0;
    *(float4*)&s_cm[w][lane * 8 + 4] = a1;
    __syncthreads();
    float* cp = cm_part + ((size_t)b * 4 + q) * HWN + hw0;
    cp[t]       = (s_cm[0][t]       + s_cm[1][t])       + (s_cm[2][t]       + s_cm[3][t]);
    cp[t + 256] = (s_cm[0][t + 256] + s_cm[1][t + 256]) + (s_cm[2][t + 256] + s_cm[3][t + 256]);
}

// ---- kB1: grid (16, 5). y<4: avg_logits k-tile matvec; y==4: cm softmax stats.
__global__ __launch_bounds__(256) void kB1(
    const float* __restrict__ Wsq, const float* __restrict__ cm_part,
    const float* __restrict__ xsum_part,
    float* __restrict__ cmstats, float* __restrict__ avg_logits)
{
    const int b = blockIdx.x, t = threadIdx.x, lane = t & 63, w = t >> 6;
    __shared__ float s_red[4];
    __shared__ float s_v[CC];
    if (blockIdx.y == 4) {
        const float* p0 = cm_part + (size_t)b * 4 * HWN;
        const float* p1 = p0 + HWN;
        const float* p2 = p1 + HWN;
        const float* p3 = p2 + HWN;
        float lmax = -1e30f;
        #pragma unroll 4
        for (int i = t; i < HWN; i += 256)
            lmax = fmaxf(lmax, (p0[i] + p1[i]) + (p2[i] + p3[i]));
        lmax = block_max(lmax, s_red);
        float lsum = 0.f;
        #pragma unroll 4
        for (int i = t; i < HWN; i += 256)
            lsum += __expf((p0[i] + p1[i]) + (p2[i] + p3[i]) - lmax);
        lsum = block_sum(lsum, s_red);
        if (t == 0) {
            cmstats[2 * b]     = lmax;
            cmstats[2 * b + 1] = __builtin_amdgcn_rcpf(lsum);
        }
    } else {
        const int k0 = blockIdx.y * 64;
        const float* xp = xsum_part + (size_t)b * 8 * CC;
        float a0 = 0.f, a1 = 0.f;
        #pragma unroll
        for (int blk = 0; blk < 8; ++blk) {
            a0 += xp[blk * CC + t];
            a1 += xp[blk * CC + t + 256];
        }
        s_v[t] = a0; s_v[t + 256] = a1;
        __syncthreads();
        float4 x0 = *(const float4*)&s_v[lane * 4];
        float4 x1 = *(const float4*)&s_v[256 + lane * 4];
        #pragma unroll 8
        for (int i = 0; i < 16; ++i) {
            const int k = k0 + w * 16 + i;
            const float* row = Wsq + (size_t)k * CC + lane * 4;
            float4 q0 = *(const float4*)(row);
            float4 q1 = *(const float4*)(row + 256);
            float s = fmaf(q0.x,x0.x, fmaf(q0.y,x0.y, fmaf(q0.z,x0.z, q0.w*x0.w)))
                    + fmaf(q1.x,x1.x, fmaf(q1.y,x1.y, fmaf(q1.z,x1.z, q1.w*x1.w)));
            s = wave_sum(s);
            if (lane == 0) avg_logits[b * INNER + k] = s * (1.0f / HWN);
        }
    }
}

// ---- k2c: softmax(avg_logits) ; wsv_eff[b,c] = sum_k sm[k]*Wsv[k,c]
__global__ __launch_bounds__(256) void k2c_wsv(
    const float* __restrict__ Wsv, const float* __restrict__ avg_logits,
    float* __restrict__ wsv_eff)
{
    const int b = blockIdx.x, t = threadIdx.x;
    const int c = blockIdx.y * 256 + t;
    __shared__ float s_red[4];
    __shared__ float s_sm[INNER];
    float a = avg_logits[b * INNER + t];
    float m = block_max(a, s_red);
    float e = __expf(a - m);
    float s2 = block_sum(e, s_red);
    s_sm[t] = e * __builtin_amdgcn_rcpf(s2);
    __syncthreads();
    float acc = 0.f;
    #pragma unroll 8
    for (int k = 0; k < INNER; ++k)
        acc = fmaf(s_sm[k], Wsv[(size_t)k * CC + c], acc);
    wsv_eff[b * CC + c] = acc;
}

// ---- kC: pass 2 over x. grid (8, 4, 16) = 512 blocks. Mirror of kA.  LDS ~44 KB.
// ctx_part[b][q][hw]; xw_part[b][hwblk][c].
__global__ __launch_bounds__(256) void kC(
    const float* __restrict__ x, const float* __restrict__ wsv_eff,
    const float* __restrict__ cm_part, const float* __restrict__ cmstats,
    float* __restrict__ ctx_part, float* __restrict__ xw_part)
{
    const int t = threadIdx.x, lane = t & 63, w = t >> 6;
    const int hw0 = blockIdx.x * 512;
    const int q   = blockIdx.y;
    const int c0  = q * 128;
    const int b   = blockIdx.z;
    __shared__ float s_w[128];
    __shared__ float s_m[512];
    __shared__ float s_cm[4][512];
    __shared__ float s_part[4][32][65];
    if (t < 128) s_w[t] = wsv_eff[b * CC + c0 + t];
    const float cmax = cmstats[2 * b], crinv = cmstats[2 * b + 1];
    {
        const size_t cb = (size_t)b * 4 * HWN + hw0;
        float cmv0 = (cm_part[cb + t]           + cm_part[cb + HWN + t])
                   + (cm_part[cb + 2*HWN + t]   + cm_part[cb + 3*HWN + t]);
        float cmv1 = (cm_part[cb + t+256]         + cm_part[cb + HWN + t+256])
                   + (cm_part[cb + 2*HWN + t+256] + cm_part[cb + 3*HWN + t+256]);
        s_m[t]       = __expf(cmv0 - cmax) * crinv;
        s_m[t + 256] = __expf(cmv1 - cmax) * crinv;
    }
    __syncthreads();
    float4 m0 = *(const float4*)&s_m[lane * 8];
    float4 m1 = *(const float4*)&s_m[lane * 8 + 4];
    const float* xb = x + ((size_t)b * CC + c0) * HWN + hw0 + lane * 8;
    float4 a0 = {0,0,0,0}, a1 = a0;
    #pragma unroll 4
    for (int ci = 0; ci < 32; ++ci) {
        const int cl = w + ci * 4;
        const float* p = xb + (size_t)cl * HWN;
        float4 v0 = *(const float4*)(p);
        float4 v1 = *(const float4*)(p + 4);
        const float wc = s_w[cl];
        a0.x = fmaf(v0.x, wc, a0.x); a0.y = fmaf(v0.y, wc, a0.y);
        a0.z = fmaf(v0.z, wc, a0.z); a0.w = fmaf(v0.w, wc, a0.w);
        a1.x = fmaf(v1.x, wc, a1.x); a1.y = fmaf(v1.y, wc, a1.y);
        a1.z = fmaf(v1.z, wc, a1.z); a1.w = fmaf(v1.w, wc, a1.w);
        s_part[w][ci][lane] =
              fmaf(v0.x,m0.x, fmaf(v0.y,m0.y, fmaf(v0.z,m0.z, v0.w*m0.w)))
            + fmaf(v1.x,m1.x, fmaf(v1.y,m1.y, fmaf(v1.z,m1.z, v1.w*m1.w)));
    }
    {
        const int r = lane & 31;
        const int j0 = (lane >> 5) * 32;
        float xs = 0.f;
        #pragma unroll
        for (int j = 0; j < 32; ++j) xs += s_part[w][r][j0 + j];
        xs += __shfl_down(xs, 32);
        if (lane < 32)
            xw_part[((size_t)b * 8 + blockIdx.x) * CC + c0 + w + r * 4] = xs;
    }
    *(float4*)&s_cm[w][lane * 8]     = a0;
    *(float4*)&s_cm[w][lane * 8 + 4] = a1;
    __syncthreads();
    float* cp = ctx_part + ((size_t)b * 4 + q) * HWN + hw0;
    cp[t]       = (s_cm[0][t]       + s_cm[1][t])       + (s_cm[2][t]       + s_cm[3][t]);
    cp[t + 256] = (s_cm[0][t + 256] + s_cm[1][t + 256]) + (s_cm[2][t + 256] + s_cm[3][t + 256]);
}

// ---- kD1: context[b,k] = Wcv[k,:512] . xw  (grid: BB x 4 k-tiles, wave-per-k)
__global__ __launch_bounds__(256) void kD1(
    const float* __restrict__ Wcv, const float* __restrict__ xw_part,
    float* __restrict__ context)
{
    const int b = blockIdx.x, t = threadIdx.x, lane = t & 63, w = t >> 6;
    const int k0 = blockIdx.y * 64;
    __shared__ float s_v[CC];
    const float* xp = xw_part + (size_t)b * 8 * CC;
    float a0 = 0.f, a1 = 0.f;
    #pragma unroll
    for (int blk = 0; blk < 8; ++blk) {
        a0 += xp[blk * CC + t];
        a1 += xp[blk * CC + t + 256];
    }
    s_v[t] = a0; s_v[t + 256] = a1;
    __syncthreads();
    float4 x0 = *(const float4*)&s_v[lane * 4];
    float4 x1 = *(const float4*)&s_v[256 + lane * 4];
    #pragma unroll 8
    for (int i = 0; i < 16; ++i) {
        const int k = k0 + w * 16 + i;
        const float* row = Wcv + (size_t)k * CC + lane * 4;
        float4 q0 = *(const float4*)(row);
        float4 q1 = *(const float4*)(row + 256);
        float s = fmaf(q0.x,x0.x, fmaf(q0.y,x0.y, fmaf(q0.z,x0.z, q0.w*x0.w)))
                + fmaf(q1.x,x1.x, fmaf(q1.y,x1.y, fmaf(q1.z,x1.z, q1.w*x1.w)));
        s = wave_sum(s);
        if (lane == 0) context[b * INNER + k] = s;
    }
}

// ---- kDf: grid (16, 5), 512 threads.
// y<4:  ctxsig[b,hw] = sigmoid(sum_q ctx_part[b,q,hw]) for hw quarter y
// y==4: z = Wcz.context (thread-per-o) -> LayerNorm -> sigmoid mask
__global__ __launch_bounds__(512) void kDf(
    const float* __restrict__ Wcz, const float* __restrict__ context,
    const float* __restrict__ gamma, const float* __restrict__ beta,
    const float* __restrict__ ctx_part, float* __restrict__ ctxsig,
    float* __restrict__ maskbuf)
{
    const int b = blockIdx.x, t = threadIdx.x;
    if (blockIdx.y < 4) {
        const int hw = blockIdx.y * 1024 + t * 2;
        const size_t pb = (size_t)b * 4 * HWN + hw;
        float2 p0 = *(const float2*)(ctx_part + pb);
        float2 p1 = *(const float2*)(ctx_part + pb + HWN);
        float2 p2 = *(const float2*)(ctx_part + pb + 2 * HWN);
        float2 p3 = *(const float2*)(ctx_part + pb + 3 * HWN);
        float2 sg;
        sg.x = fsigmoid((p0.x + p1.x) + (p2.x + p3.x));
        sg.y = fsigmoid((p0.y + p1.y) + (p2.y + p3.y));
        *(float2*)(ctxsig + (size_t)b * HWN + hw) = sg;
        return;
    }
    __shared__ float s_red[8];
    __shared__ float s_ctx[INNER];
    if (t < INNER) s_ctx[t] = context[b * INNER + t];
    __syncthreads();
    float z;
    {
        const float* wr = Wcz + (size_t)t * INNER;
        float d = 0.f;
        #pragma unroll 8
        for (int k = 0; k < INNER; ++k) d = fmaf(wr[k], s_ctx[k], d);
        z = d;
    }
    float mu = block_sum8(z, s_red) * (1.f / CC);
    float d = z - mu;
    float var = block_sum8(d * d, s_red) * (1.f / CC);
    float rstd = rsqrtf(var + EPSV);
    maskbuf[b * CC + t] = fsigmoid(fmaf(d * rstd, gamma[t], beta[t]));
}

// ---- kE: pass 3 over x. out = x * (mask[c] + ctxsig[hw]).
__global__ __launch_bounds__(256) void kE(
    const float* __restrict__ x, const float* __restrict__ ctxsig,
    const float* __restrict__ maskbuf, float* __restrict__ out)
{
    const int t  = threadIdx.x;
    const int hw = blockIdx.x * 1024 + t * 4;
    const int c0 = blockIdx.y * 16;
    const int b  = blockIdx.z;
    float4 sg = *(const float4*)(ctxsig + (size_t)b * HWN + hw);
    const float* mb = maskbuf + b * CC + c0;
    const size_t base = ((size_t)b * CC + c0) * HWN + hw;
    #pragma unroll 4
    for (int ci = 0; ci < 16; ++ci) {
        const float m = mb[ci];
        float4 xv = *(const float4*)(x + base + (size_t)ci * HWN);
        float4 o;
        o.x = xv.x * (m + sg.x);
        o.y = xv.y * (m + sg.y);
        o.z = xv.z * (m + sg.z);
        o.w = xv.w * (m + sg.w);
        *(float4*)(out + base + (size_t)ci * HWN) = o;
    }
}

extern "C" void kernel_launch(void* const* d_in, const int* in_sizes, int n_in,
                              void* d_out, int out_size, void* d_ws, size_t ws_size,
                              hipStream_t stream) {
    const float* x     = (const float*)d_in[0];
    const float* Wsq   = (const float*)d_in[1];
    const float* Wsv   = (const float*)d_in[2];
    const float* Wcq   = (const float*)d_in[3];
    const float* Wcv   = (const float*)d_in[4];
    const float* Wcz   = (const float*)d_in[5];
    const float* gamma = (const float*)d_in[6];
    const float* beta  = (const float*)d_in[7];
    float* out = (float*)d_out;
    float* ws  = (float*)d_ws;

    float* cm_part    = ws;            // [16][4][4096] = 262144
    float* xsum_part  = ws + 262144;   // [16][8][512]  = 65536 (reused as xw_part)
    float* ctx_part   = ws + 327680;   // [16][4][4096] = 262144
    float* cmstats    = ws + 589824;   // 32
    float* wsv_eff    = ws + 589856;   // 8192
    float* avg_logits = ws + 598048;   // 4096
    float* context    = ws + 602144;   // 4096
    float* ctxsig     = ws + 606240;   // [16][4096] = 65536
    float* maskbuf    = ws + 671776;   // 8192
    // total ~679968 floats (~2.7 MiB); fully written before read — no memset

    kA<<<dim3(8, 4, BB), 256, 0, stream>>>(x, Wcq, cm_part, xsum_part);
    kB1<<<dim3(BB, 5), 256, 0, stream>>>(Wsq, cm_part, xsum_part, cmstats, avg_logits);
    k2c_wsv<<<dim3(BB, 2), 256, 0, stream>>>(Wsv, avg_logits, wsv_eff);
    kC<<<dim3(8, 4, BB), 256, 0, stream>>>(x, wsv_eff, cm_part, cmstats, ctx_part, xsum_part);
    kD1<<<dim3(BB, 4), 256, 0, stream>>>(Wcv, xsum_part, context);
    kDf<<<dim3(BB, 5), 512, 0, stream>>>(Wcz, context, gamma, beta, ctx_part, ctxsig, maskbuf);
    kE<<<dim3(4, 32, BB), 256, 0, stream>>>(x, ctxsig, maskbuf, out);
}